// Round 15
// baseline (618.789 us; speedup 1.0000x reference)
//
#include <hip/hip_runtime.h>

typedef unsigned int uint;
typedef unsigned short ushort;
typedef __attribute__((ext_vector_type(8))) short bf16x8;   // 8 bf16 (4 VGPRs)
typedef __attribute__((ext_vector_type(4))) float f32x4;    // MFMA accumulator
typedef __attribute__((ext_vector_type(4))) int int4v;      // native vector (valid for nontemporal builtin)

constexpr int N_ = 100000;   // nodes
constexpr int E_ = 1600000;  // edges
constexpr int G_ = 2048;     // graphs
constexpr int H_ = 128;      // hidden
constexpr int WPSZ = 16384;  // ushorts per packed 128x128 bf16 weight
constexpr int NSLICE = 8;    // dst-space slices == XCD count
constexpr int SL_SZ = N_ / NSLICE;   // 12500 nodes per slice
constexpr int SL_BLOCKS = 256;       // blocks per slice-group
constexpr int CAP = 64;      // padded CSR capacity per node (Poisson(16): P(deg>64) ~ 1e-19)
constexpr int CLDS = 136;    // padded C-tile row stride in ushorts (272B: 16B-aligned, bank-spread)

// ---------------- bf16 helpers ----------------
__device__ inline ushort f2bf(float f) {
    uint u = __builtin_bit_cast(uint, f);
    u += 0x7fffu + ((u >> 16) & 1u);   // RNE
    return (ushort)(u >> 16);
}
__device__ inline float bflo(uint v) { return __builtin_bit_cast(float, v << 16); }
__device__ inline float bfhi(uint v) { return __builtin_bit_cast(float, v & 0xffff0000u); }

// ---------------- CSR build: single fill pass, XCD-sliced, int4 non-temporal reads ----------------
__global__ __launch_bounds__(256) void k_fill_c(const int* __restrict__ srcv, const int* __restrict__ dstv,
                                                int* __restrict__ cnt, int* __restrict__ csr_src) {
    int slice = blockIdx.x & (NSLICE - 1);
    int grp   = blockIdx.x >> 3;
    int lo = slice * SL_SZ, hi = lo + SL_SZ;
    int stride = SL_BLOCKS * 256;
    const int4v* d4 = (const int4v*)dstv;
    const int4v* s4 = (const int4v*)srcv;
    int nq = E_ / 4;
    for (int q = grp * 256 + threadIdx.x; q < nq; q += stride) {
        int4v d = __builtin_nontemporal_load(&d4[q]);
        int4v s = __builtin_nontemporal_load(&s4[q]);
        #pragma unroll
        for (int k = 0; k < 4; k++) {
            int dd = d[k];
            int ss = s[k];
            if (dd >= lo && dd < hi) {
                int slot = atomicAdd(&cnt[dd], 1);
                if (slot < CAP) csr_src[(size_t)dd * CAP + slot] = ss;
            }
        }
    }
}

// ---------------- weight pack: W[128][128] f32 -> B-fragment order bf16 ----------------
__global__ __launch_bounds__(64) void k_pack(const float* __restrict__ W, ushort* __restrict__ Wp) {
    int lane = threadIdx.x;
    int n = ((blockIdx.x >> 2) * 16) + (lane & 15);
    int k0 = (blockIdx.x & 3) * 32 + (lane >> 4) * 8;
    bf16x8 v;
    #pragma unroll
    for (int j = 0; j < 8; j++) v[j] = (short)f2bf(W[(size_t)(k0 + j) * H_ + n]);
    *(bf16x8*)&Wp[(size_t)(blockIdx.x * 64 + lane) * 8] = v;
}

// ---------------- MFMA GEMM: out[M,128] = relu?(in[M,128] @ W + b) ----------------
// C written via LDS staging (reuses W buffer after barrier) -> coalesced 16B stores.
template <bool F32IN, bool RELU>
__global__ __launch_bounds__(256) void k_mm(const void* __restrict__ in, const ushort* __restrict__ Wp,
                                            const float* __restrict__ bias, ushort* __restrict__ out, int M) {
    __shared__ ushort sm[128 * CLDS];   // 34 KiB: holds packed W (16384), then the C tile
    int t = threadIdx.x;
    #pragma unroll
    for (int i = 0; i < 8; i++) {
        int idx = i * 256 + t;
        *(bf16x8*)&sm[(size_t)idx * 8] = *(const bf16x8*)&Wp[(size_t)idx * 8];
    }
    __syncthreads();

    int wave = t >> 6, lane = t & 63;
    int col = lane & 15, kc = lane >> 4;
    int row0 = blockIdx.x * 128 + wave * 32;

    float bv[8];
    #pragma unroll
    for (int nt = 0; nt < 8; nt++) bv[nt] = bias[nt * 16 + col];

    f32x4 acc[2][8];
    #pragma unroll
    for (int rt = 0; rt < 2; rt++)
        #pragma unroll
        for (int nt = 0; nt < 8; nt++) {
            acc[rt][nt][0] = bv[nt]; acc[rt][nt][1] = bv[nt];
            acc[rt][nt][2] = bv[nt]; acc[rt][nt][3] = bv[nt];
        }

    #pragma unroll
    for (int kb = 0; kb < 4; kb++) {
        bf16x8 bf[8];
        #pragma unroll
        for (int nt = 0; nt < 8; nt++)
            bf[nt] = *(const bf16x8*)&sm[(size_t)(((nt * 4 + kb) * 64) + lane) * 8];
        #pragma unroll
        for (int rt = 0; rt < 2; rt++) {
            int r = row0 + rt * 16 + col;
            if (r > M - 1) r = M - 1;   // clamp reads; stores guarded below
            bf16x8 af;
            if (F32IN) {
                const float* fin = (const float*)in;
                float4 a0 = *(const float4*)&fin[(size_t)r * H_ + kb * 32 + kc * 8];
                float4 a1 = *(const float4*)&fin[(size_t)r * H_ + kb * 32 + kc * 8 + 4];
                af[0] = (short)f2bf(a0.x); af[1] = (short)f2bf(a0.y);
                af[2] = (short)f2bf(a0.z); af[3] = (short)f2bf(a0.w);
                af[4] = (short)f2bf(a1.x); af[5] = (short)f2bf(a1.y);
                af[6] = (short)f2bf(a1.z); af[7] = (short)f2bf(a1.w);
            } else {
                af = *(const bf16x8*)&((const ushort*)in)[(size_t)r * H_ + kb * 32 + kc * 8];
            }
            #pragma unroll
            for (int nt = 0; nt < 8; nt++)
                acc[rt][nt] = __builtin_amdgcn_mfma_f32_16x16x32_bf16(af, bf[nt], acc[rt][nt], 0, 0, 0);
        }
    }

    // ---- C tile -> LDS (all waves done with W) ----
    __syncthreads();
    // D layout: col = lane&15, local row = wave*32 + rt*16 + kc*4 + r
    #pragma unroll
    for (int rt = 0; rt < 2; rt++) {
        int rl0 = wave * 32 + rt * 16 + kc * 4;
        #pragma unroll
        for (int r = 0; r < 4; r++) {
            #pragma unroll
            for (int nt = 0; nt < 8; nt++) {
                float f = acc[rt][nt][r];
                if (RELU) f = fmaxf(f, 0.f);
                sm[(size_t)(rl0 + r) * CLDS + nt * 16 + col] = f2bf(f);
            }
        }
    }
    __syncthreads();

    // ---- coalesced store: 2048 x 16B chunks ----
    int base_row = blockIdx.x * 128;
    #pragma unroll
    for (int i = 0; i < 8; i++) {
        int ch = i * 256 + t;            // 0..2047
        int row = ch >> 4, part = ch & 15;
        if (base_row + row < M) {
            bf16x8 v = *(const bf16x8*)&sm[(size_t)row * CLDS + part * 8];
            *(bf16x8*)&out[(size_t)(base_row + row) * H_ + part * 8] = v;
        }
    }
}

// ---------------- GIN aggregation (bf16, padded CSR), 8-deep unrolled gather ----------------
__global__ __launch_bounds__(256) void k_agg(const uint* __restrict__ h, const int* __restrict__ cnt,
                                             const int* __restrict__ csr_src, const float* __restrict__ eps,
                                             int layer, uint* __restrict__ z) {
    int node = blockIdx.x * 4 + (threadIdx.x >> 6);
    int c = threadIdx.x & 63;
    int deg = cnt[node];
    if (deg > CAP) deg = CAP;
    const int* cs = csr_src + (size_t)node * CAP;
    float a0 = 0.f, a1 = 0.f;
    int j = 0;
    for (; j + 8 <= deg; j += 8) {
        int4v i0 = *(const int4v*)&cs[j];
        int4v i1 = *(const int4v*)&cs[j + 4];
        uint v0 = h[(size_t)i0[0] * 64 + c];
        uint v1 = h[(size_t)i0[1] * 64 + c];
        uint v2 = h[(size_t)i0[2] * 64 + c];
        uint v3 = h[(size_t)i0[3] * 64 + c];
        uint v4 = h[(size_t)i1[0] * 64 + c];
        uint v5 = h[(size_t)i1[1] * 64 + c];
        uint v6 = h[(size_t)i1[2] * 64 + c];
        uint v7 = h[(size_t)i1[3] * 64 + c];
        a0 += bflo(v0) + bflo(v1) + bflo(v2) + bflo(v3) + bflo(v4) + bflo(v5) + bflo(v6) + bflo(v7);
        a1 += bfhi(v0) + bfhi(v1) + bfhi(v2) + bfhi(v3) + bfhi(v4) + bfhi(v5) + bfhi(v6) + bfhi(v7);
    }
    for (; j + 4 <= deg; j += 4) {
        int4v i0 = *(const int4v*)&cs[j];
        uint v0 = h[(size_t)i0[0] * 64 + c];
        uint v1 = h[(size_t)i0[1] * 64 + c];
        uint v2 = h[(size_t)i0[2] * 64 + c];
        uint v3 = h[(size_t)i0[3] * 64 + c];
        a0 += bflo(v0) + bflo(v1) + bflo(v2) + bflo(v3);
        a1 += bfhi(v0) + bfhi(v1) + bfhi(v2) + bfhi(v3);
    }
    for (; j < deg; j++) {
        uint v = h[(size_t)cs[j] * 64 + c];
        a0 += bflo(v); a1 += bfhi(v);
    }
    float e1 = 1.0f + eps[layer];
    uint hv = h[(size_t)node * 64 + c];
    float o0 = fmaf(e1, bflo(hv), a0);
    float o1 = fmaf(e1, bfhi(hv), a1);
    z[(size_t)node * 64 + c] = (uint)f2bf(o0) | ((uint)f2bf(o1) << 16);
}

// ---------------- fp32 Linear for small (G-row) GEMMs ----------------
template <int KDIM, int NDIM, bool RELU>
__global__ __launch_bounds__(256) void k_lin(const float* __restrict__ in, const float* __restrict__ W,
                                             const float* __restrict__ bias, float* __restrict__ out) {
    constexpr int CV = NDIM / 4;
    constexpr int RPI = 256 / CV;
    constexpr int R = 4;
    constexpr int ROWS = RPI * R;
    __shared__ float4 Wl[KDIM * CV];
    for (int i = threadIdx.x; i < KDIM * CV; i += 256) Wl[i] = ((const float4*)W)[i];
    __syncthreads();

    int cv = threadIdx.x % CV;
    int rg = threadIdx.x / CV;
    int row0 = blockIdx.x * ROWS + rg * R;

    float4 bv = ((const float4*)bias)[cv];
    float4 acc[R];
    #pragma unroll
    for (int r = 0; r < R; r++) acc[r] = bv;

    const float4* in4 = (const float4*)in;
    #pragma unroll 2
    for (int k4 = 0; k4 < KDIM / 4; k4++) {
        float4 w0 = Wl[(4 * k4 + 0) * CV + cv];
        float4 w1 = Wl[(4 * k4 + 1) * CV + cv];
        float4 w2 = Wl[(4 * k4 + 2) * CV + cv];
        float4 w3 = Wl[(4 * k4 + 3) * CV + cv];
        #pragma unroll
        for (int r = 0; r < R; r++) {
            float4 a = in4[(size_t)(row0 + r) * (KDIM / 4) + k4];
            acc[r].x = fmaf(a.x, w0.x, fmaf(a.y, w1.x, fmaf(a.z, w2.x, fmaf(a.w, w3.x, acc[r].x))));
            acc[r].y = fmaf(a.x, w0.y, fmaf(a.y, w1.y, fmaf(a.z, w2.y, fmaf(a.w, w3.y, acc[r].y))));
            acc[r].z = fmaf(a.x, w0.z, fmaf(a.y, w1.z, fmaf(a.z, w2.z, fmaf(a.w, w3.z, acc[r].z))));
            acc[r].w = fmaf(a.x, w0.w, fmaf(a.y, w1.w, fmaf(a.z, w2.w, fmaf(a.w, w3.w, acc[r].w))));
        }
    }
    #pragma unroll
    for (int r = 0; r < R; r++) {
        float4 o = acc[r];
        if (RELU) {
            o.x = fmaxf(o.x, 0.f); o.y = fmaxf(o.y, 0.f);
            o.z = fmaxf(o.z, 0.f); o.w = fmaxf(o.w, 0.f);
        }
        ((float4*)out)[(size_t)(row0 + r) * CV + cv] = o;
    }
}

// ---------------- Pooling (sorted batch), vectorized: 64 lanes x uint (2 cols) ----------------
__global__ __launch_bounds__(64) void k_pool(const uint* __restrict__ h2, const int* __restrict__ batch,
                                             float* __restrict__ pooled, float* __restrict__ gcnt, int n) {
    int c = threadIdx.x;                 // col pair 0..63
    int base = blockIdx.x * 128;
    int nmax = min(base + 128, n);
    int gcur = batch[base];
    float a0 = 0.f, a1 = 0.f;
    int run = 0;
    for (int i = base; i < nmax; i++) {
        int g = batch[i];
        if (g != gcur) {
            atomicAdd(&pooled[(size_t)gcur * 128 + 2 * c], a0);
            atomicAdd(&pooled[(size_t)gcur * 128 + 2 * c + 1], a1);
            if (c == 0) atomicAdd(&gcnt[gcur], (float)run);
            a0 = 0.f; a1 = 0.f; run = 0; gcur = g;
        }
        uint v = h2[(size_t)i * 64 + c];
        a0 += bflo(v); a1 += bfhi(v);
        run++;
    }
    atomicAdd(&pooled[(size_t)gcur * 128 + 2 * c], a0);
    atomicAdd(&pooled[(size_t)gcur * 128 + 2 * c + 1], a1);
    if (c == 0) atomicAdd(&gcnt[gcur], (float)run);
}

__global__ __launch_bounds__(256) void k_div(float* __restrict__ pooled, const float* __restrict__ gcnt) {
    int i = blockIdx.x * 256 + threadIdx.x;
    float cnt = fmaxf(gcnt[i >> 7], 1.0f);
    pooled[i] = pooled[i] / cnt;
}

// ---------------- Scatter decoded per-graph rows to nodes ----------------
__global__ __launch_bounds__(256) void k_scatter(const float* __restrict__ recong, const int* __restrict__ batch,
                                                 float* __restrict__ out) {
    int i = blockIdx.x * 256 + threadIdx.x;
    int node = i >> 5;
    int c4 = i & 31;
    int g = batch[node];
    ((float4*)out)[(size_t)node * 32 + c4] = ((const float4*)recong)[(size_t)g * 32 + c4];
}

// ---------------- launch ----------------

extern "C" void kernel_launch(void* const* d_in, const int* in_sizes, int n_in,
                              void* d_out, int out_size, void* d_ws, size_t ws_size,
                              hipStream_t stream) {
    const float* x     = (const float*)d_in[0];
    const int*   ei    = (const int*)d_in[1];
    const int*   batch = (const int*)d_in[2];
    const float* W_in  = (const float*)d_in[3];
    const float* b_in  = (const float*)d_in[4];
    const float* Ws1   = (const float*)d_in[5];
    const float* bs1   = (const float*)d_in[6];
    const float* Ws2   = (const float*)d_in[7];
    const float* bs2   = (const float*)d_in[8];
    const float* eps   = (const float*)d_in[9];
    const float* W_out = (const float*)d_in[10];
    const float* b_out = (const float*)d_in[11];
    const float* Wd1   = (const float*)d_in[12];
    const float* bd1   = (const float*)d_in[13];
    const float* Wd2   = (const float*)d_in[14];
    const float* bd2   = (const float*)d_in[15];

    const int* srcv = ei;
    const int* dstv = ei + E_;

    char* ws = (char*)d_ws;
    size_t off = 0;
    auto nextp = [&](size_t bytes) -> char* {
        char* p = ws + off;
        off += (bytes + 255) & ~(size_t)255;
        return p;
    };
    ushort* buf0    = (ushort*)nextp((size_t)N_ * H_ * 2);
    ushort* buf1    = (ushort*)nextp((size_t)N_ * H_ * 2);
    ushort* Wp      = (ushort*)nextp((size_t)7 * WPSZ * 2);
    int*   cnt      = (int*)nextp((size_t)N_ * 4);
    int*   csr_src  = (int*)nextp((size_t)N_ * CAP * 4);   // 25.6 MB padded CSR
    float* pooled   = (float*)nextp((size_t)G_ * H_ * 4);
    float* gcnt     = (float*)nextp((size_t)G_ * 4);
    float* tg       = (float*)nextp((size_t)G_ * 64 * 4);
    float* recong   = (float*)nextp((size_t)G_ * H_ * 4);

    float* out_recon = (float*)d_out;
    float* out_ge    = (float*)d_out + (size_t)N_ * H_;

    (void)hipMemsetAsync(cnt, 0, (size_t)N_ * 4, stream);
    (void)hipMemsetAsync(pooled, 0, (size_t)G_ * H_ * 4, stream);
    (void)hipMemsetAsync(gcnt, 0, (size_t)G_ * 4, stream);

    // ---- CSR build: single sliced fill pass ----
    k_fill_c<<<NSLICE * SL_BLOCKS, 256, 0, stream>>>(srcv, dstv, cnt, csr_src);

    // ---- pack weights ----
    k_pack<<<32, 64, 0, stream>>>(W_in, Wp + 0 * WPSZ);
    for (int l = 0; l < 3; l++) {
        k_pack<<<32, 64, 0, stream>>>(Ws1 + (size_t)l * H_ * H_, Wp + (size_t)(1 + 2 * l) * WPSZ);
        k_pack<<<32, 64, 0, stream>>>(Ws2 + (size_t)l * H_ * H_, Wp + (size_t)(2 + 2 * l) * WPSZ);
    }

    int mmgrid = (N_ + 127) / 128;

    // ---- input projection (fp32 in, converts in-reg) ----
    k_mm<true, true><<<mmgrid, 256, 0, stream>>>(x, Wp, b_in, buf0, N_);

    // ---- GIN layers ----
    ushort* hb = buf0;
    ushort* ob = buf1;
    for (int l = 0; l < 3; l++) {
        k_agg<<<N_ / 4, 256, 0, stream>>>((const uint*)hb, cnt, csr_src, eps, l, (uint*)ob);
        k_mm<false, true><<<mmgrid, 256, 0, stream>>>(ob, Wp + (size_t)(1 + 2 * l) * WPSZ, bs1 + l * H_, hb, N_);
        k_mm<false, true><<<mmgrid, 256, 0, stream>>>(hb, Wp + (size_t)(2 + 2 * l) * WPSZ, bs2 + l * H_, ob, N_);
        ushort* tmp = hb; hb = ob; ob = tmp;
    }

    // ---- pool + output projection (fp32) ----
    k_pool<<<(N_ + 127) / 128, 64, 0, stream>>>((const uint*)hb, batch, pooled, gcnt, N_);
    k_div<<<G_ * H_ / 256, 256, 0, stream>>>(pooled, gcnt);
    k_lin<128, 128, false><<<G_ / 32, 256, 0, stream>>>(pooled, W_out, b_out, out_ge);

    // ---- decoder on per-graph rows, then scatter ----
    k_lin<128, 64, true><<<G_ / 64, 256, 0, stream>>>(out_ge, Wd1, bd1, tg);
    k_lin<64, 128, false><<<G_ / 32, 256, 0, stream>>>(tg, Wd2, bd2, recong);
    k_scatter<<<(size_t)N_ * 32 / 256, 256, 0, stream>>>(recong, batch, out_recon);
}

// Round 16
// 551.380 us; speedup vs baseline: 1.1223x; 1.1223x over previous
//
#include <hip/hip_runtime.h>

typedef unsigned int uint;
typedef unsigned short ushort;
typedef __attribute__((ext_vector_type(8))) short bf16x8;   // 8 bf16 (4 VGPRs)
typedef __attribute__((ext_vector_type(4))) float f32x4;    // MFMA accumulator
typedef __attribute__((ext_vector_type(4))) int int4v;      // native vector (valid for nontemporal builtin)

constexpr int N_ = 100000;   // nodes
constexpr int E_ = 1600000;  // edges
constexpr int G_ = 2048;     // graphs
constexpr int H_ = 128;      // hidden
constexpr int WPSZ = 16384;  // ushorts per packed 128x128 bf16 weight
constexpr int NSLICE = 8;    // dst-space slices == XCD count
constexpr int SL_SZ = N_ / NSLICE;   // 12500 nodes per slice
constexpr int SL_BLOCKS = 256;       // blocks per slice-group
constexpr int CAP = 64;      // padded CSR capacity per node (Poisson(16): P(deg>64) ~ 1e-19)
constexpr int CLDS = 132;    // padded tile row stride in ushorts (264B -> 66-dword stride, ~2-way banks)

// ---------------- bf16 helpers ----------------
__device__ inline ushort f2bf(float f) {
    uint u = __builtin_bit_cast(uint, f);
    u += 0x7fffu + ((u >> 16) & 1u);   // RNE
    return (ushort)(u >> 16);
}
__device__ inline float bflo(uint v) { return __builtin_bit_cast(float, v << 16); }
__device__ inline float bfhi(uint v) { return __builtin_bit_cast(float, v & 0xffff0000u); }

// ---------------- zero accumulators (one launch) ----------------
__global__ __launch_bounds__(256) void k_zero(int* __restrict__ cnt, float* __restrict__ pooled,
                                              float* __restrict__ gcnt) {
    int i = blockIdx.x * 256 + threadIdx.x;
    if (i < N_) cnt[i] = 0;
    else if (i < N_ + G_ * H_) pooled[i - N_] = 0.f;
    else if (i < N_ + G_ * H_ + G_) gcnt[i - N_ - G_ * H_] = 0.f;
}

// ---------------- CSR build: single fill pass, XCD-sliced, int4 non-temporal reads ----------------
__global__ __launch_bounds__(256) void k_fill_c(const int* __restrict__ srcv, const int* __restrict__ dstv,
                                                int* __restrict__ cnt, int* __restrict__ csr_src) {
    int slice = blockIdx.x & (NSLICE - 1);
    int grp   = blockIdx.x >> 3;
    int lo = slice * SL_SZ, hi = lo + SL_SZ;
    int stride = SL_BLOCKS * 256;
    const int4v* d4 = (const int4v*)dstv;
    const int4v* s4 = (const int4v*)srcv;
    int nq = E_ / 4;
    for (int q = grp * 256 + threadIdx.x; q < nq; q += stride) {
        int4v d = __builtin_nontemporal_load(&d4[q]);
        int4v s = __builtin_nontemporal_load(&s4[q]);
        #pragma unroll
        for (int k = 0; k < 4; k++) {
            int dd = d[k];
            int ss = s[k];
            if (dd >= lo && dd < hi) {
                int slot = atomicAdd(&cnt[dd], 1);
                if (slot < CAP) csr_src[(size_t)dd * CAP + slot] = ss;
            }
        }
    }
}

// ---------------- weight pack: all 7 W[128][128] f32 -> B-fragment order bf16, one launch ----------------
// slot 0 = W_in; slot 1+2l = Ws1[l]; slot 2+2l = Ws2[l]
__global__ __launch_bounds__(64) void k_pack_all(const float* __restrict__ W_in, const float* __restrict__ Ws1,
                                                 const float* __restrict__ Ws2, ushort* __restrict__ Wp) {
    int m = blockIdx.x >> 5;        // weight index 0..6
    int sub = blockIdx.x & 31;      // sub-tile 0..31
    const float* W;
    if (m == 0) W = W_in;
    else if (m & 1) W = Ws1 + (size_t)((m - 1) >> 1) * H_ * H_;
    else W = Ws2 + (size_t)((m >> 1) - 1) * H_ * H_;
    ushort* dst = Wp + (size_t)m * WPSZ;

    int lane = threadIdx.x;
    int n = ((sub >> 2) * 16) + (lane & 15);
    int k0 = (sub & 3) * 32 + (lane >> 4) * 8;
    bf16x8 v;
    #pragma unroll
    for (int j = 0; j < 8; j++) v[j] = (short)f2bf(W[(size_t)(k0 + j) * H_ + n]);
    *(bf16x8*)&dst[(size_t)(sub * 64 + lane) * 8] = v;
}

// ---------------- MFMA GEMM (input projection): out[M,128] = relu(in_f32[M,128] @ W + b) ----------------
__global__ __launch_bounds__(256) void k_mm_in(const float* __restrict__ in, const ushort* __restrict__ Wp,
                                               const float* __restrict__ bias, ushort* __restrict__ out, int M) {
    __shared__ ushort sm[128 * CLDS];
    int t = threadIdx.x;
    #pragma unroll
    for (int i = 0; i < 8; i++) {
        int idx = i * 256 + t;   // 2048 x 16B = whole packed W
        *(bf16x8*)&sm[(size_t)idx * 8] = *(const bf16x8*)&Wp[(size_t)idx * 8];
    }
    __syncthreads();

    int wave = t >> 6, lane = t & 63;
    int col = lane & 15, kc = lane >> 4;
    int row0 = blockIdx.x * 128 + wave * 32;

    float bv[8];
    #pragma unroll
    for (int nt = 0; nt < 8; nt++) bv[nt] = bias[nt * 16 + col];

    f32x4 acc[2][8];
    #pragma unroll
    for (int rt = 0; rt < 2; rt++)
        #pragma unroll
        for (int nt = 0; nt < 8; nt++) {
            acc[rt][nt][0] = bv[nt]; acc[rt][nt][1] = bv[nt];
            acc[rt][nt][2] = bv[nt]; acc[rt][nt][3] = bv[nt];
        }

    #pragma unroll
    for (int kb = 0; kb < 4; kb++) {
        bf16x8 bf[8];
        #pragma unroll
        for (int nt = 0; nt < 8; nt++)
            bf[nt] = *(const bf16x8*)&sm[(size_t)(((nt * 4 + kb) * 64) + lane) * 8];
        #pragma unroll
        for (int rt = 0; rt < 2; rt++) {
            int r = row0 + rt * 16 + col;
            if (r > M - 1) r = M - 1;
            float4 a0 = *(const float4*)&in[(size_t)r * H_ + kb * 32 + kc * 8];
            float4 a1 = *(const float4*)&in[(size_t)r * H_ + kb * 32 + kc * 8 + 4];
            bf16x8 af;
            af[0] = (short)f2bf(a0.x); af[1] = (short)f2bf(a0.y);
            af[2] = (short)f2bf(a0.z); af[3] = (short)f2bf(a0.w);
            af[4] = (short)f2bf(a1.x); af[5] = (short)f2bf(a1.y);
            af[6] = (short)f2bf(a1.z); af[7] = (short)f2bf(a1.w);
            #pragma unroll
            for (int nt = 0; nt < 8; nt++)
                acc[rt][nt] = __builtin_amdgcn_mfma_f32_16x16x32_bf16(af, bf[nt], acc[rt][nt], 0, 0, 0);
        }
    }

    __syncthreads();   // done with W; reuse sm for C tile
    #pragma unroll
    for (int rt = 0; rt < 2; rt++) {
        int rl0 = wave * 32 + rt * 16 + kc * 4;
        #pragma unroll
        for (int r = 0; r < 4; r++)
            #pragma unroll
            for (int nt = 0; nt < 8; nt++)
                sm[(size_t)(rl0 + r) * CLDS + nt * 16 + col] = f2bf(fmaxf(acc[rt][nt][r], 0.f));
    }
    __syncthreads();

    int base_row = blockIdx.x * 128;
    #pragma unroll
    for (int i = 0; i < 8; i++) {
        int ch = i * 256 + t;
        int row = ch >> 4, part = ch & 15;
        if (base_row + row < M)
            *(bf16x8*)&out[(size_t)(base_row + row) * H_ + part * 8] =
                *(const bf16x8*)&sm[(size_t)row * CLDS + part * 8];
    }
}

// ---------------- Fused GIN MLP: out = relu(relu(z@W1+b1)@W2+b2), t staged in LDS ----------------
// B-fragments read directly from packed global Wp (L2-resident); LDS holds only the t/C tile.
// Each wave owns rows [wave*32, wave*32+32) of the 128-row block -> LDS tile is wave-private.
__global__ __launch_bounds__(256) void k_mlp(const ushort* __restrict__ in,
                                             const ushort* __restrict__ Wp1, const float* __restrict__ b1,
                                             const ushort* __restrict__ Wp2, const float* __restrict__ b2,
                                             ushort* __restrict__ out, int M) {
    __shared__ ushort sm[128 * CLDS];
    int t = threadIdx.x;
    int wave = t >> 6, lane = t & 63;
    int col = lane & 15, kc = lane >> 4;
    int row0 = blockIdx.x * 128 + wave * 32;

    // ---- stage 1: t = relu(z @ W1 + b1) ----
    f32x4 acc[2][8];
    #pragma unroll
    for (int nt = 0; nt < 8; nt++) {
        float b = b1[nt * 16 + col];
        #pragma unroll
        for (int rt = 0; rt < 2; rt++) {
            acc[rt][nt][0] = b; acc[rt][nt][1] = b;
            acc[rt][nt][2] = b; acc[rt][nt][3] = b;
        }
    }
    #pragma unroll
    for (int kb = 0; kb < 4; kb++) {
        bf16x8 bf[8];
        #pragma unroll
        for (int nt = 0; nt < 8; nt++)
            bf[nt] = *(const bf16x8*)&Wp1[(size_t)(((nt * 4 + kb) * 64) + lane) * 8];
        #pragma unroll
        for (int rt = 0; rt < 2; rt++) {
            int r = row0 + rt * 16 + col;
            if (r > M - 1) r = M - 1;
            bf16x8 af = *(const bf16x8*)&in[(size_t)r * H_ + kb * 32 + kc * 8];
            #pragma unroll
            for (int nt = 0; nt < 8; nt++)
                acc[rt][nt] = __builtin_amdgcn_mfma_f32_16x16x32_bf16(af, bf[nt], acc[rt][nt], 0, 0, 0);
        }
    }
    // write t (bf16, relu) into wave-private LDS rows, D-layout scatter
    #pragma unroll
    for (int rt = 0; rt < 2; rt++) {
        int rl0 = wave * 32 + rt * 16 + kc * 4;
        #pragma unroll
        for (int r = 0; r < 4; r++)
            #pragma unroll
            for (int nt = 0; nt < 8; nt++)
                sm[(size_t)(rl0 + r) * CLDS + nt * 16 + col] = f2bf(fmaxf(acc[rt][nt][r], 0.f));
    }
    __syncthreads();   // conservative (deps are wave-private)

    // ---- stage 2: h = relu(t @ W2 + b2) ----
    #pragma unroll
    for (int nt = 0; nt < 8; nt++) {
        float b = b2[nt * 16 + col];
        #pragma unroll
        for (int rt = 0; rt < 2; rt++) {
            acc[rt][nt][0] = b; acc[rt][nt][1] = b;
            acc[rt][nt][2] = b; acc[rt][nt][3] = b;
        }
    }
    #pragma unroll
    for (int kb = 0; kb < 4; kb++) {
        bf16x8 bf[8];
        #pragma unroll
        for (int nt = 0; nt < 8; nt++)
            bf[nt] = *(const bf16x8*)&Wp2[(size_t)(((nt * 4 + kb) * 64) + lane) * 8];
        #pragma unroll
        for (int rt = 0; rt < 2; rt++) {
            bf16x8 af = *(const bf16x8*)&sm[(size_t)(wave * 32 + rt * 16 + col) * CLDS + kb * 32 + kc * 8];
            #pragma unroll
            for (int nt = 0; nt < 8; nt++)
                acc[rt][nt] = __builtin_amdgcn_mfma_f32_16x16x32_bf16(af, bf[nt], acc[rt][nt], 0, 0, 0);
        }
    }
    // overwrite own LDS rows with final C (all stage-2 reads of t done in this wave)
    #pragma unroll
    for (int rt = 0; rt < 2; rt++) {
        int rl0 = wave * 32 + rt * 16 + kc * 4;
        #pragma unroll
        for (int r = 0; r < 4; r++)
            #pragma unroll
            for (int nt = 0; nt < 8; nt++)
                sm[(size_t)(rl0 + r) * CLDS + nt * 16 + col] = f2bf(fmaxf(acc[rt][nt][r], 0.f));
    }
    // per-wave coalesced store of its 32 rows (16B/lane)
    #pragma unroll
    for (int i = 0; i < 8; i++) {
        int ch = i * 64 + lane;                 // 0..511
        int row = wave * 32 + (ch >> 4);        // own rows only
        int part = ch & 15;
        int grow = blockIdx.x * 128 + row;
        if (grow < M)
            *(bf16x8*)&out[(size_t)grow * H_ + part * 8] =
                *(const bf16x8*)&sm[(size_t)row * CLDS + part * 8];
    }
}

// ---------------- GIN aggregation: 32 lanes/node (uint2 = 4 cols/lane), 8 nodes/block ----------------
__global__ __launch_bounds__(256) void k_agg(const uint2* __restrict__ h, const int* __restrict__ cnt,
                                             const int* __restrict__ csr_src, const float* __restrict__ eps,
                                             int layer, uint2* __restrict__ z) {
    int node = blockIdx.x * 8 + (threadIdx.x >> 5);
    int c = threadIdx.x & 31;
    int deg = cnt[node];
    if (deg > CAP) deg = CAP;
    const int* cs = csr_src + (size_t)node * CAP;
    float a0 = 0.f, a1 = 0.f, a2 = 0.f, a3 = 0.f;
    int j = 0;
    for (; j + 8 <= deg; j += 8) {
        int4v i0 = *(const int4v*)&cs[j];
        int4v i1 = *(const int4v*)&cs[j + 4];
        #pragma unroll
        for (int k = 0; k < 4; k++) {
            uint2 v = h[(size_t)i0[k] * 32 + c];
            a0 += bflo(v.x); a1 += bfhi(v.x); a2 += bflo(v.y); a3 += bfhi(v.y);
        }
        #pragma unroll
        for (int k = 0; k < 4; k++) {
            uint2 v = h[(size_t)i1[k] * 32 + c];
            a0 += bflo(v.x); a1 += bfhi(v.x); a2 += bflo(v.y); a3 += bfhi(v.y);
        }
    }
    for (; j + 4 <= deg; j += 4) {
        int4v i0 = *(const int4v*)&cs[j];
        #pragma unroll
        for (int k = 0; k < 4; k++) {
            uint2 v = h[(size_t)i0[k] * 32 + c];
            a0 += bflo(v.x); a1 += bfhi(v.x); a2 += bflo(v.y); a3 += bfhi(v.y);
        }
    }
    for (; j < deg; j++) {
        uint2 v = h[(size_t)cs[j] * 32 + c];
        a0 += bflo(v.x); a1 += bfhi(v.x); a2 += bflo(v.y); a3 += bfhi(v.y);
    }
    float e1 = 1.0f + eps[layer];
    uint2 hv = h[(size_t)node * 32 + c];
    float o0 = fmaf(e1, bflo(hv.x), a0);
    float o1 = fmaf(e1, bfhi(hv.x), a1);
    float o2 = fmaf(e1, bflo(hv.y), a2);
    float o3 = fmaf(e1, bfhi(hv.y), a3);
    uint2 ov;
    ov.x = (uint)f2bf(o0) | ((uint)f2bf(o1) << 16);
    ov.y = (uint)f2bf(o2) | ((uint)f2bf(o3) << 16);
    z[(size_t)node * 32 + c] = ov;
}

// ---------------- fp32 Linear for small (G-row) GEMMs ----------------
template <int KDIM, int NDIM, bool RELU>
__global__ __launch_bounds__(256) void k_lin(const float* __restrict__ in, const float* __restrict__ W,
                                             const float* __restrict__ bias, float* __restrict__ out) {
    constexpr int CV = NDIM / 4;
    constexpr int RPI = 256 / CV;
    constexpr int R = 4;
    constexpr int ROWS = RPI * R;
    __shared__ float4 Wl[KDIM * CV];
    for (int i = threadIdx.x; i < KDIM * CV; i += 256) Wl[i] = ((const float4*)W)[i];
    __syncthreads();

    int cv = threadIdx.x % CV;
    int rg = threadIdx.x / CV;
    int row0 = blockIdx.x * ROWS + rg * R;

    float4 bv = ((const float4*)bias)[cv];
    float4 acc[R];
    #pragma unroll
    for (int r = 0; r < R; r++) acc[r] = bv;

    const float4* in4 = (const float4*)in;
    #pragma unroll 2
    for (int k4 = 0; k4 < KDIM / 4; k4++) {
        float4 w0 = Wl[(4 * k4 + 0) * CV + cv];
        float4 w1 = Wl[(4 * k4 + 1) * CV + cv];
        float4 w2 = Wl[(4 * k4 + 2) * CV + cv];
        float4 w3 = Wl[(4 * k4 + 3) * CV + cv];
        #pragma unroll
        for (int r = 0; r < R; r++) {
            float4 a = in4[(size_t)(row0 + r) * (KDIM / 4) + k4];
            acc[r].x = fmaf(a.x, w0.x, fmaf(a.y, w1.x, fmaf(a.z, w2.x, fmaf(a.w, w3.x, acc[r].x))));
            acc[r].y = fmaf(a.x, w0.y, fmaf(a.y, w1.y, fmaf(a.z, w2.y, fmaf(a.w, w3.y, acc[r].y))));
            acc[r].z = fmaf(a.x, w0.z, fmaf(a.y, w1.z, fmaf(a.z, w2.z, fmaf(a.w, w3.z, acc[r].z))));
            acc[r].w = fmaf(a.x, w0.w, fmaf(a.y, w1.w, fmaf(a.z, w2.w, fmaf(a.w, w3.w, acc[r].w))));
        }
    }
    #pragma unroll
    for (int r = 0; r < R; r++) {
        float4 o = acc[r];
        if (RELU) {
            o.x = fmaxf(o.x, 0.f); o.y = fmaxf(o.y, 0.f);
            o.z = fmaxf(o.z, 0.f); o.w = fmaxf(o.w, 0.f);
        }
        ((float4*)out)[(size_t)(row0 + r) * CV + cv] = o;
    }
}

// ---------------- Pooling (sorted batch), 64 lanes x uint (2 cols) ----------------
__global__ __launch_bounds__(64) void k_pool(const uint* __restrict__ h2, const int* __restrict__ batch,
                                             float* __restrict__ pooled, float* __restrict__ gcnt, int n) {
    int c = threadIdx.x;
    int base = blockIdx.x * 128;
    int nmax = min(base + 128, n);
    int gcur = batch[base];
    float a0 = 0.f, a1 = 0.f;
    int run = 0;
    for (int i = base; i < nmax; i++) {
        int g = batch[i];
        if (g != gcur) {
            atomicAdd(&pooled[(size_t)gcur * 128 + 2 * c], a0);
            atomicAdd(&pooled[(size_t)gcur * 128 + 2 * c + 1], a1);
            if (c == 0) atomicAdd(&gcnt[gcur], (float)run);
            a0 = 0.f; a1 = 0.f; run = 0; gcur = g;
        }
        uint v = h2[(size_t)i * 64 + c];
        a0 += bflo(v); a1 += bfhi(v);
        run++;
    }
    atomicAdd(&pooled[(size_t)gcur * 128 + 2 * c], a0);
    atomicAdd(&pooled[(size_t)gcur * 128 + 2 * c + 1], a1);
    if (c == 0) atomicAdd(&gcnt[gcur], (float)run);
}

__global__ __launch_bounds__(256) void k_div(float* __restrict__ pooled, const float* __restrict__ gcnt) {
    int i = blockIdx.x * 256 + threadIdx.x;
    float cnt = fmaxf(gcnt[i >> 7], 1.0f);
    pooled[i] = pooled[i] / cnt;
}

// ---------------- Scatter decoded per-graph rows to nodes ----------------
__global__ __launch_bounds__(256) void k_scatter(const float* __restrict__ recong, const int* __restrict__ batch,
                                                 float* __restrict__ out) {
    int i = blockIdx.x * 256 + threadIdx.x;
    int node = i >> 5;
    int c4 = i & 31;
    int g = batch[node];
    ((float4*)out)[(size_t)node * 32 + c4] = ((const float4*)recong)[(size_t)g * 32 + c4];
}

// ---------------- launch ----------------

extern "C" void kernel_launch(void* const* d_in, const int* in_sizes, int n_in,
                              void* d_out, int out_size, void* d_ws, size_t ws_size,
                              hipStream_t stream) {
    const float* x     = (const float*)d_in[0];
    const int*   ei    = (const int*)d_in[1];
    const int*   batch = (const int*)d_in[2];
    const float* W_in  = (const float*)d_in[3];
    const float* b_in  = (const float*)d_in[4];
    const float* Ws1   = (const float*)d_in[5];
    const float* bs1   = (const float*)d_in[6];
    const float* Ws2   = (const float*)d_in[7];
    const float* bs2   = (const float*)d_in[8];
    const float* eps   = (const float*)d_in[9];
    const float* W_out = (const float*)d_in[10];
    const float* b_out = (const float*)d_in[11];
    const float* Wd1   = (const float*)d_in[12];
    const float* bd1   = (const float*)d_in[13];
    const float* Wd2   = (const float*)d_in[14];
    const float* bd2   = (const float*)d_in[15];

    const int* srcv = ei;
    const int* dstv = ei + E_;

    char* ws = (char*)d_ws;
    size_t off = 0;
    auto nextp = [&](size_t bytes) -> char* {
        char* p = ws + off;
        off += (bytes + 255) & ~(size_t)255;
        return p;
    };
    ushort* buf0    = (ushort*)nextp((size_t)N_ * H_ * 2);
    ushort* buf1    = (ushort*)nextp((size_t)N_ * H_ * 2);
    ushort* Wp      = (ushort*)nextp((size_t)7 * WPSZ * 2);
    int*   cnt      = (int*)nextp((size_t)N_ * 4);
    int*   csr_src  = (int*)nextp((size_t)N_ * CAP * 4);   // 25.6 MB padded CSR
    float* pooled   = (float*)nextp((size_t)G_ * H_ * 4);
    float* gcnt     = (float*)nextp((size_t)G_ * 4);
    float* tg       = (float*)nextp((size_t)G_ * 64 * 4);
    float* recong   = (float*)nextp((size_t)G_ * H_ * 4);

    float* out_recon = (float*)d_out;
    float* out_ge    = (float*)d_out + (size_t)N_ * H_;

    // ---- zero accumulators (one launch) ----
    int zgrid = (N_ + G_ * H_ + G_ + 255) / 256;
    k_zero<<<zgrid, 256, 0, stream>>>(cnt, pooled, gcnt);

    // ---- CSR build: single sliced fill pass ----
    k_fill_c<<<NSLICE * SL_BLOCKS, 256, 0, stream>>>(srcv, dstv, cnt, csr_src);

    // ---- pack all 7 weights (one launch) ----
    k_pack_all<<<7 * 32, 64, 0, stream>>>(W_in, Ws1, Ws2, Wp);

    int mmgrid = (N_ + 127) / 128;

    // ---- input projection (fp32 in, converts in-reg) ----
    k_mm_in<<<mmgrid, 256, 0, stream>>>(x, Wp, b_in, buf0, N_);

    // ---- GIN layers: agg (buf0->buf1), fused MLP (buf1->buf0) ----
    for (int l = 0; l < 3; l++) {
        k_agg<<<N_ / 8, 256, 0, stream>>>((const uint2*)buf0, cnt, csr_src, eps, l, (uint2*)buf1);
        k_mlp<<<mmgrid, 256, 0, stream>>>(buf1,
                                          Wp + (size_t)(1 + 2 * l) * WPSZ, bs1 + l * H_,
                                          Wp + (size_t)(2 + 2 * l) * WPSZ, bs2 + l * H_,
                                          buf0, N_);
    }

    // ---- pool + output projection (fp32) ----
    k_pool<<<(N_ + 127) / 128, 64, 0, stream>>>((const uint*)buf0, batch, pooled, gcnt, N_);
    k_div<<<G_ * H_ / 256, 256, 0, stream>>>(pooled, gcnt);
    k_lin<128, 128, false><<<G_ / 32, 256, 0, stream>>>(pooled, W_out, b_out, out_ge);

    // ---- decoder on per-graph rows, then scatter ----
    k_lin<128, 64, true><<<G_ / 64, 256, 0, stream>>>(out_ge, Wd1, bd1, tg);
    k_lin<64, 128, false><<<G_ / 32, 256, 0, stream>>>(tg, Wd2, bd2, recong);
    k_scatter<<<(size_t)N_ * 32 / 256, 256, 0, stream>>>(recong, batch, out_recon);
}